// Round 4
// baseline (336.867 us; speedup 1.0000x reference)
//
#include <hip/hip_runtime.h>

// out[k, n] = dot(x[n, 0:4], W[k, 0:4]) + b[k],  k in [0,32), N = 2e6.
// R3 (resubmit; prior round hit GPU-acquisition timeout): fillBuffer-like
// write pattern — each block owns ONE head and ONE contiguous row-chunk,
// so its stores form a single linear stream (the pattern the 6.4 TB/s
// poison fill uses). x chunks are re-read once per head but are
// L2/L3-resident (32 MB total); consecutive blocks (x-major grid: heads
// fastest) share the same chunk across heads, so each XCD's L2 pulls each
// chunk once. HBM: 32 MB read + 256 MB write.

constexpr int K      = 32;
constexpr int NCHUNK = 64;   // row-chunks; grid = (K, NCHUNK) = 2048 blocks

typedef float f32x4 __attribute__((ext_vector_type(4)));

__global__ __launch_bounds__(256) void bignet_kernel(
    const float* __restrict__ x,
    const float* __restrict__ W,
    const float* __restrict__ b,
    float* __restrict__ out,
    int n4,        // number of 4-row groups (N/4)
    int N,         // total rows
    int cpb)       // 4-row groups per chunk
{
    const int k  = blockIdx.x;                 // head (fastest grid dim)
    const int g0 = blockIdx.y * cpb;           // chunk start (4-row groups)
    const int g1 = min(g0 + cpb, n4);

    const f32x4 w  = reinterpret_cast<const f32x4*>(W)[k];   // uniform
    const float bk = b[k];

    const f32x4* x4 = reinterpret_cast<const f32x4*>(x);
    f32x4* ok = reinterpret_cast<f32x4*>(out + (size_t)k * N); // 16B-aligned

    #pragma unroll 2
    for (int g = g0 + (int)threadIdx.x; g < g1; g += 256) {
        const f32x4 x0 = x4[(size_t)g * 4 + 0];
        const f32x4 x1 = x4[(size_t)g * 4 + 1];
        const f32x4 x2 = x4[(size_t)g * 4 + 2];
        const f32x4 x3 = x4[(size_t)g * 4 + 3];

        f32x4 o;
        o.x = fmaf(x0.x, w.x, fmaf(x0.y, w.y, fmaf(x0.z, w.z, fmaf(x0.w, w.w, bk))));
        o.y = fmaf(x1.x, w.x, fmaf(x1.y, w.y, fmaf(x1.z, w.z, fmaf(x1.w, w.w, bk))));
        o.z = fmaf(x2.x, w.x, fmaf(x2.y, w.y, fmaf(x2.z, w.z, fmaf(x2.w, w.w, bk))));
        o.w = fmaf(x3.x, w.x, fmaf(x3.y, w.y, fmaf(x3.z, w.z, fmaf(x3.w, w.w, bk))));

        // Single linear store stream per block (fill-like); NT keeps the
        // 256 MB output from evicting the hot x chunks out of L2.
        __builtin_nontemporal_store(o, ok + g);
    }
}

extern "C" void kernel_launch(void* const* d_in, const int* in_sizes, int n_in,
                              void* d_out, int out_size, void* d_ws, size_t ws_size,
                              hipStream_t stream) {
    const float* x = (const float*)d_in[0];   // [N, 4]
    const float* W = (const float*)d_in[1];   // [32, 1, 4]
    const float* b = (const float*)d_in[2];   // [32, 1]
    float* out = (float*)d_out;               // [32, N, 1]

    const int N   = in_sizes[0] / 4;          // 2,000,000
    const int n4  = N / 4;                    // 500,000
    const int cpb = (n4 + NCHUNK - 1) / NCHUNK;

    dim3 grid(K, NCHUNK);                     // heads fastest -> chunk shared
    bignet_kernel<<<grid, 256, 0, stream>>>(x, W, b, out, n4, N, cpb);
}

// Round 9
// 283.178 us; speedup vs baseline: 1.1896x; 1.1896x over previous
//
#include <hip/hip_runtime.h>

// out[k, n] = dot(x[n, 0:4], W[k, 0:4]) + b[k],  k in [0,32), N = 2e6.
// R4 resubmit #4 (five GPU-acquisition timeouts in a row): R2 structure
// (traffic-optimal: x read once, 8 write streams/block) with PLAIN
// stores instead of nontemporal — single-variable A/B vs R2's 280.2 us.
// fillBuffer hits 6.4 TB/s with plain stores; NT's L2-no-allocate may
// defeat write-combining.

constexpr int K  = 32;
constexpr int D  = 4;
constexpr int KB = 8;   // heads per block (grid.y = K/KB = 4)

typedef float f32x4 __attribute__((ext_vector_type(4)));

__global__ __launch_bounds__(256) void bignet_kernel(
    const float* __restrict__ x,
    const float* __restrict__ W,
    const float* __restrict__ b,
    float* __restrict__ out,
    int n4,        // number of 4-row groups (N/4)
    int N)         // total rows
{
    const int g = blockIdx.x * blockDim.x + threadIdx.x;
    if (g >= n4) return;
    const int k0 = blockIdx.y * KB;

    // 4 consecutive rows of x: 64 contiguous bytes per thread (read ONCE).
    const f32x4* x4 = reinterpret_cast<const f32x4*>(x);
    const f32x4 x0 = x4[(size_t)g * 4 + 0];
    const f32x4 x1 = x4[(size_t)g * 4 + 1];
    const f32x4 x2 = x4[(size_t)g * 4 + 2];
    const f32x4 x3 = x4[(size_t)g * 4 + 3];

    const f32x4* W4 = reinterpret_cast<const f32x4*>(W);

    #pragma unroll
    for (int kk = 0; kk < KB; ++kk) {
        const int k = k0 + kk;
        const f32x4 w = W4[k];       // block-uniform -> scalar loads
        const float bk = b[k];

        f32x4 o;
        o.x = fmaf(x0.x, w.x, fmaf(x0.y, w.y, fmaf(x0.z, w.z, fmaf(x0.w, w.w, bk))));
        o.y = fmaf(x1.x, w.x, fmaf(x1.y, w.y, fmaf(x1.z, w.z, fmaf(x1.w, w.w, bk))));
        o.z = fmaf(x2.x, w.x, fmaf(x2.y, w.y, fmaf(x2.z, w.z, fmaf(x2.w, w.w, bk))));
        o.w = fmaf(x3.x, w.x, fmaf(x3.y, w.y, fmaf(x3.z, w.z, fmaf(x3.w, w.w, bk))));

        // out + k*N is 16B-aligned (k*8,000,000 B). Coalesced 1KB/wave
        // per head; PLAIN store (L2 write-allocate + combine, like fill).
        f32x4* ok = reinterpret_cast<f32x4*>(out + (size_t)k * N);
        ok[g] = o;
    }
}

extern "C" void kernel_launch(void* const* d_in, const int* in_sizes, int n_in,
                              void* d_out, int out_size, void* d_ws, size_t ws_size,
                              hipStream_t stream) {
    const float* x = (const float*)d_in[0];   // [N, 4]
    const float* W = (const float*)d_in[1];   // [32, 1, 4]
    const float* b = (const float*)d_in[2];   // [32, 1]
    float* out = (float*)d_out;               // [32, N, 1]

    const int N  = in_sizes[0] / D;           // 2,000,000
    const int n4 = N / 4;                     // 500,000

    const int block = 256;
    dim3 grid((n4 + block - 1) / block, K / KB);
    bignet_kernel<<<grid, block, 0, stream>>>(x, W, b, out, n4, N);
}